// Round 2
// baseline (13173.250 us; speedup 1.0000x reference)
//
#include <hip/hip_runtime.h>
#include <stdint.h>

#define S_LEN 1024
#define B_N   128
#define E_N   10
#define H_N   256
#define L_N   4
#define G4    1024   // 4*H

using short8 = __attribute__((ext_vector_type(8))) short;
using f32x4  = __attribute__((ext_vector_type(4))) float;

__device__ __forceinline__ unsigned short f2bf(float x){
    unsigned int u = __builtin_bit_cast(unsigned int, x);
    u = (u + 0x7FFFu + ((u >> 16) & 1u)) >> 16;   // RNE
    return (unsigned short)u;
}

// ---- convert f32 weights -> bf16 ----
__global__ void k_cvt(const float* __restrict__ src, unsigned short* __restrict__ dst, int n){
    int i = blockIdx.x*256 + threadIdx.x;
    if (i < n) dst[i] = f2bf(src[i]);
}

// ---- s[t][b][e] = relu((e01[x]+p01[t]) @ f01_w.T + f01_b) ----
__global__ void k_prep_s(const int* __restrict__ x, const float* __restrict__ e01,
                         const float* __restrict__ p01, const float* __restrict__ f01w,
                         const float* __restrict__ f01b, float* __restrict__ s){
    int idx = blockIdx.x*256 + threadIdx.x;   // t*128+b
    int t = idx >> 7;
    int tok = x[idx];
    float v[E_N];
    #pragma unroll
    for (int e=0;e<E_N;e++) v[e] = e01[tok*E_N+e] + p01[t*E_N+e];
    #pragma unroll
    for (int eo=0;eo<E_N;eo++){
        float a = f01b[eo];
        #pragma unroll
        for (int e=0;e<E_N;e++) a += v[e]*f01w[eo*E_N+e];
        s[(size_t)idx*E_N+eo] = a > 0.f ? a : 0.f;
    }
}

// ---- ssum[b][e] = sum_t s[t][b][e] ----
__global__ void k_ssum(const float* __restrict__ s, float* __restrict__ ssum){
    __shared__ float red[256][E_N];
    int b = blockIdx.x; int tid = threadIdx.x;
    float acc[E_N] = {};
    for (int t = tid; t < S_LEN; t += 256){
        const float* p = s + ((size_t)t*B_N + b)*E_N;
        #pragma unroll
        for (int e=0;e<E_N;e++) acc[e] += p[e];
    }
    #pragma unroll
    for (int e=0;e<E_N;e++) red[tid][e] = acc[e];
    __syncthreads();
    for (int st=128; st>0; st>>=1){
        if (tid < st){
            #pragma unroll
            for (int e=0;e<E_N;e++) red[tid][e] += red[tid+st][e];
        }
        __syncthreads();
    }
    if (tid < E_N) ssum[b*E_N+tid] = red[0][tid];
}

// ---- h0/c0 (relu MLPs on ssum), scatter into state buffers ----
__global__ void k_init(const float* __restrict__ ssum, const float* __restrict__ f02w,
                       const float* __restrict__ f02b, const float* __restrict__ f03w,
                       const float* __restrict__ f03b,
                       unsigned short* __restrict__ Hbuf, float* __restrict__ C){
    int b = blockIdx.x, j = threadIdx.x;   // j in [0,1024)
    float sv[E_N];
    #pragma unroll
    for (int e=0;e<E_N;e++) sv[e] = ssum[b*E_N+e];
    float h = f02b[j], c = f03b[j];
    #pragma unroll
    for (int e=0;e<E_N;e++){ h += sv[e]*f02w[j*E_N+e]; c += sv[e]*f03w[j*E_N+e]; }
    h = h > 0.f ? h : 0.f;
    c = c > 0.f ? c : 0.f;
    int l = j >> 8, k = j & 255;
    // layer l is first read at wall-step w=l from parity (l&1)
    Hbuf[(((size_t)l*2 + (l&1))*B_N + b)*H_N + k] = f2bf(h);
    C[((size_t)l*B_N + b)*H_N + k] = c;
}

// ---- bias sum + zero the sync slots ----
__global__ void k_bias(const float* __restrict__ bih, const float* __restrict__ bhh,
                       float* __restrict__ bsum, int* __restrict__ slots){
    int i = blockIdx.x*256 + threadIdx.x;   // 4096
    bsum[i] = bih[i] + bhh[i];
    if (i < 256) slots[i] = 0;
}

// ---- persistent wavefront LSTM ----
// grid 256 WGs: bg = bid&7 (sync group / XCD heuristic), kj = (bid>>3)&7, l = bid>>6
// block 256 = 4 waves; wave = gate. Weights live in VGPRs, c in registers.
__global__ __launch_bounds__(256) void k_lstm(
    const float* __restrict__ s,            // [S][B][E] f32
    const unsigned short* __restrict__ Wih, // [3][1024][256] bf16 (layers 1..3)
    const unsigned short* __restrict__ Whh, // [4][1024][256] bf16
    const float* __restrict__ Wih0,         // [1024][10] f32
    const float* __restrict__ bsum,         // [4][1024] f32
    unsigned short* __restrict__ Hbuf,      // [4][2][128][256] bf16
    const float* __restrict__ C,            // [4][128][256] f32 (init only)
    float* __restrict__ y,                  // [128][1024] f32 out
    int* slots)                             // [8][32] step flags
{
    __shared__ unsigned short hx[16*264];   // h tile, stride 264 (bank-safe)
    __shared__ unsigned short xx[16*264];   // x tile (layers>=1)
    __shared__ float xs[16*E_N];            // layer-0 s tile
    __shared__ float gl[16*132];            // gates tile (stride 132, bank-safe)

    const int bid = blockIdx.x;
    const int bg = bid & 7, kj = (bid >> 3) & 7, l = bid >> 6;
    const int b0 = bg*16, k0 = kj*32;
    const int tid = threadIdx.x;
    const int wid = tid >> 6, lane = tid & 63;
    const int cl = lane & 15, kg = lane >> 4;
    const int j0 = wid*256 + k0 + cl, j1 = j0 + 16;

    const float bia0 = bsum[l*G4 + j0];
    const float bia1 = bsum[l*G4 + j1];

    // ---- weights -> registers (once) ----
    short8 wh0[8], wh1[8], wi0[8], wi1[8];
    {
        const unsigned short* p0 = Whh + ((size_t)l*G4 + j0)*H_N + kg*8;
        const unsigned short* p1 = Whh + ((size_t)l*G4 + j1)*H_N + kg*8;
        #pragma unroll
        for (int kt=0;kt<8;kt++){
            wh0[kt] = *(const short8*)(p0 + kt*32);
            wh1[kt] = *(const short8*)(p1 + kt*32);
        }
    }
    float w00[E_N], w01[E_N];
    if (l > 0){
        const unsigned short* q0 = Wih + ((size_t)(l-1)*G4 + j0)*H_N + kg*8;
        const unsigned short* q1 = Wih + ((size_t)(l-1)*G4 + j1)*H_N + kg*8;
        #pragma unroll
        for (int kt=0;kt<8;kt++){
            wi0[kt] = *(const short8*)(q0 + kt*32);
            wi1[kt] = *(const short8*)(q1 + kt*32);
        }
    } else {
        #pragma unroll
        for (int e=0;e<E_N;e++){
            w00[e] = Wih0[j0*E_N + e];
            w01[e] = Wih0[j1*E_N + e];
        }
    }

    // ---- private cell state in registers ----
    const int e0 = tid, e1 = tid + 256;
    const int br0 = e0 >> 5, ko0 = e0 & 31;
    const int br1 = e1 >> 5, ko1 = e1 & 31;
    const size_t ho0 = ((size_t)(l*2))*B_N*H_N + (size_t)(b0+br0)*H_N + k0 + ko0;
    const size_t ho1 = ((size_t)(l*2))*B_N*H_N + (size_t)(b0+br1)*H_N + k0 + ko1;
    float c0r = C[((size_t)l*B_N + b0 + br0)*H_N + k0 + ko0];
    float c1r = C[((size_t)l*B_N + b0 + br1)*H_N + k0 + ko1];

    int* const myslot  = slots + bg*32 + l*8 + kj;
    int* const bgslots = slots + bg*32;
    const size_t BH = (size_t)B_N * H_N;

    for (int w = 0; w < S_LEN + L_N - 1; ++w){
        const int t = w - l;
        const int p = w & 1;
        if (t >= 0 && t < S_LEN){
            // stage h (and x) tiles into LDS
            {
                const int r = tid >> 4, cs = tid & 15;
                const unsigned short* src = Hbuf + ((size_t)(l*2 + p))*BH + (size_t)(b0+r)*H_N + cs*16;
                *(uint4*)&hx[r*264 + cs*16]     = *(const uint4*)src;
                *(uint4*)&hx[r*264 + cs*16 + 8] = *(const uint4*)(src + 8);
                if (l > 0){
                    const unsigned short* sx = Hbuf + ((size_t)((l-1)*2 + p))*BH + (size_t)(b0+r)*H_N + cs*16;
                    *(uint4*)&xx[r*264 + cs*16]     = *(const uint4*)sx;
                    *(uint4*)&xx[r*264 + cs*16 + 8] = *(const uint4*)(sx + 8);
                } else if (tid < 16*E_N){
                    xs[tid] = s[((size_t)t*B_N + b0 + tid/E_N)*E_N + (tid%E_N)];
                }
            }
            __syncthreads();

            f32x4 acc0 = {0.f,0.f,0.f,0.f};
            f32x4 acc1 = {0.f,0.f,0.f,0.f};
            if (l > 0){
                #pragma unroll
                for (int kt=0;kt<8;kt++){
                    const int kk = kt*32 + kg*8;
                    short8 ah = *(const short8*)&hx[cl*264 + kk];
                    short8 ax = *(const short8*)&xx[cl*264 + kk];
                    acc0 = __builtin_amdgcn_mfma_f32_16x16x32_bf16(ah, wh0[kt], acc0, 0,0,0);
                    acc1 = __builtin_amdgcn_mfma_f32_16x16x32_bf16(ah, wh1[kt], acc1, 0,0,0);
                    acc0 = __builtin_amdgcn_mfma_f32_16x16x32_bf16(ax, wi0[kt], acc0, 0,0,0);
                    acc1 = __builtin_amdgcn_mfma_f32_16x16x32_bf16(ax, wi1[kt], acc1, 0,0,0);
                }
            } else {
                #pragma unroll
                for (int kt=0;kt<8;kt++){
                    const int kk = kt*32 + kg*8;
                    short8 ah = *(const short8*)&hx[cl*264 + kk];
                    acc0 = __builtin_amdgcn_mfma_f32_16x16x32_bf16(ah, wh0[kt], acc0, 0,0,0);
                    acc1 = __builtin_amdgcn_mfma_f32_16x16x32_bf16(ah, wh1[kt], acc1, 0,0,0);
                }
            }

            #pragma unroll
            for (int r=0;r<4;r++){
                const int br = kg*4 + r;       // D: row=(lane>>4)*4+reg (batch), col=lane&15
                float v0 = acc0[r] + bia0;
                float v1 = acc1[r] + bia1;
                if (l == 0){
                    #pragma unroll
                    for (int e=0;e<E_N;e++){
                        const float sv = xs[br*E_N + e];
                        v0 += sv*w00[e];
                        v1 += sv*w01[e];
                    }
                }
                gl[br*132 + wid*32 + cl]      = v0;
                gl[br*132 + wid*32 + 16 + cl] = v1;
            }
            __syncthreads();

            // cell update: 2 private elements per thread
            {
                float gi = gl[br0*132 +      ko0];
                float gf = gl[br0*132 + 32 + ko0];
                float gg = gl[br0*132 + 64 + ko0];
                float go = gl[br0*132 + 96 + ko0];
                float si = 1.f/(1.f + __expf(-gi));
                float sf = 1.f/(1.f + __expf(-gf));
                float sg = tanhf(gg);
                float so = 1.f/(1.f + __expf(-go));
                c0r = sf*c0r + si*sg;
                float hn = so*tanhf(c0r);
                Hbuf[ho0 + (size_t)(p^1)*BH] = f2bf(hn);
                if (t == S_LEN-1) y[(size_t)(b0+br0)*G4 + l*H_N + k0 + ko0] = hn;
            }
            {
                float gi = gl[br1*132 +      ko1];
                float gf = gl[br1*132 + 32 + ko1];
                float gg = gl[br1*132 + 64 + ko1];
                float go = gl[br1*132 + 96 + ko1];
                float si = 1.f/(1.f + __expf(-gi));
                float sf = 1.f/(1.f + __expf(-gf));
                float sg = tanhf(gg);
                float so = 1.f/(1.f + __expf(-go));
                c1r = sf*c1r + si*sg;
                float hn = so*tanhf(c1r);
                Hbuf[ho1 + (size_t)(p^1)*BH] = f2bf(hn);
                if (t == S_LEN-1) y[(size_t)(b0+br1)*G4 + l*H_N + k0 + ko1] = hn;
            }
        }
        __syncthreads();   // all lanes' stores drained (vmcnt 0) before flag
        if (tid == 0){
            __threadfence();                       // agent-scope: flush L2 writebacks
            __hip_atomic_store(myslot, w+1, __ATOMIC_RELEASE, __HIP_MEMORY_SCOPE_AGENT);
        }
        if (wid == 0){
            const int target = w + 1;
            int guard = 0;
            for(;;){
                int v = (lane < 32)
                    ? __hip_atomic_load(bgslots + lane, __ATOMIC_ACQUIRE, __HIP_MEMORY_SCOPE_AGENT)
                    : target;
                if (__all(v >= target)) break;
                if (++guard > (1<<16)) break;      // hang guard (never hit when co-resident)
            }
        }
        __syncthreads();
    }
}

extern "C" void kernel_launch(void* const* d_in, const int* in_sizes, int n_in,
                              void* d_out, int out_size, void* d_ws, size_t ws_size,
                              hipStream_t stream) {
    const int*   x      = (const int*)  d_in[0];
    const float* e01    = (const float*)d_in[1];
    const float* p01    = (const float*)d_in[2];
    const float* f01w   = (const float*)d_in[3];
    const float* f01b   = (const float*)d_in[4];
    const float* f02w   = (const float*)d_in[5];
    const float* f02b   = (const float*)d_in[6];
    const float* f03w   = (const float*)d_in[7];
    const float* f03b   = (const float*)d_in[8];
    const float* Wih0   = (const float*)d_in[9];
    const float* WihR   = (const float*)d_in[10];  // [3][1024][256]
    const float* Whh    = (const float*)d_in[11];  // [4][1024][256]
    const float* bih    = (const float*)d_in[12];
    const float* bhh    = (const float*)d_in[13];
    float* y = (float*)d_out;

    // workspace carve
    float* s_buf = (float*)d_ws;                          // 1,310,720 f
    float* ssum  = s_buf + (size_t)S_LEN*B_N*E_N;         // 1,280 f
    float* bsum  = ssum + B_N*E_N;                        // 4,096 f
    float* Cst   = bsum + L_N*G4;                         // 131,072 f
    int*   slots = (int*)(Cst + (size_t)L_N*B_N*H_N);     // 256 i
    unsigned short* Hbuf = (unsigned short*)(slots + 256);          // 262,144 us
    unsigned short* WbHH = Hbuf + (size_t)L_N*2*B_N*H_N;            // 1,048,576 us
    unsigned short* WbIH = WbHH + (size_t)L_N*G4*H_N;               // 786,432 us

    // weight conversion
    k_cvt<<<dim3(4096), dim3(256), 0, stream>>>(Whh,  WbHH, L_N*G4*H_N);
    k_cvt<<<dim3(3072), dim3(256), 0, stream>>>(WihR, WbIH, (L_N-1)*G4*H_N);

    // prologue
    k_prep_s<<<dim3((S_LEN*B_N)/256), dim3(256), 0, stream>>>(x, e01, p01, f01w, f01b, s_buf);
    k_ssum  <<<dim3(B_N), dim3(256), 0, stream>>>(s_buf, ssum);
    k_init  <<<dim3(B_N), dim3(1024), 0, stream>>>(ssum, f02w, f02b, f03w, f03b, Hbuf, Cst);
    k_bias  <<<dim3(16), dim3(256), 0, stream>>>(bih, bhh, bsum, slots);

    // persistent wavefront LSTM (one dispatch, co-resident grid)
    {
        const float* s_p = s_buf;
        const unsigned short* wih_p = WbIH;
        const unsigned short* whh_p = WbHH;
        const float* wih0_p = Wih0;
        const float* bsum_p = bsum;
        unsigned short* hbuf_p = Hbuf;
        const float* c_p = Cst;
        float* y_p = y;
        int* slots_p = slots;
        void* args[] = { &s_p, &wih_p, &whh_p, &wih0_p, &bsum_p, &hbuf_p, &c_p, &y_p, &slots_p };
        hipLaunchCooperativeKernel(reinterpret_cast<const void*>(&k_lstm),
                                   dim3(256), dim3(256), args, 0, stream);
    }
}

// Round 3
// 3870.612 us; speedup vs baseline: 3.4034x; 3.4034x over previous
//
#include <hip/hip_runtime.h>
#include <stdint.h>

#define S_LEN 1024
#define B_N   128
#define E_N   10
#define H_N   256
#define L_N   4
#define G4    1024   // 4*H

using short8 = __attribute__((ext_vector_type(8))) short;
using f32x4  = __attribute__((ext_vector_type(4))) float;

__device__ __forceinline__ unsigned short f2bf(float x){
    unsigned int u = __builtin_bit_cast(unsigned int, x);
    u = (u + 0x7FFFu + ((u >> 16) & 1u)) >> 16;   // RNE
    return (unsigned short)u;
}

// ---- convert f32 weights -> bf16 ----
__global__ void k_cvt(const float* __restrict__ src, unsigned short* __restrict__ dst, int n){
    int i = blockIdx.x*256 + threadIdx.x;
    if (i < n) dst[i] = f2bf(src[i]);
}

// ---- s[t][b][e] = relu((e01[x]+p01[t]) @ f01_w.T + f01_b) ----
__global__ void k_prep_s(const int* __restrict__ x, const float* __restrict__ e01,
                         const float* __restrict__ p01, const float* __restrict__ f01w,
                         const float* __restrict__ f01b, float* __restrict__ s){
    int idx = blockIdx.x*256 + threadIdx.x;   // t*128+b
    int t = idx >> 7;
    int tok = x[idx];
    float v[E_N];
    #pragma unroll
    for (int e=0;e<E_N;e++) v[e] = e01[tok*E_N+e] + p01[t*E_N+e];
    #pragma unroll
    for (int eo=0;eo<E_N;eo++){
        float a = f01b[eo];
        #pragma unroll
        for (int e=0;e<E_N;e++) a += v[e]*f01w[eo*E_N+e];
        s[(size_t)idx*E_N+eo] = a > 0.f ? a : 0.f;
    }
}

// ---- ssum[b][e] = sum_t s[t][b][e] ----
__global__ void k_ssum(const float* __restrict__ s, float* __restrict__ ssum){
    __shared__ float red[256][E_N];
    int b = blockIdx.x; int tid = threadIdx.x;
    float acc[E_N] = {};
    for (int t = tid; t < S_LEN; t += 256){
        const float* p = s + ((size_t)t*B_N + b)*E_N;
        #pragma unroll
        for (int e=0;e<E_N;e++) acc[e] += p[e];
    }
    #pragma unroll
    for (int e=0;e<E_N;e++) red[tid][e] = acc[e];
    __syncthreads();
    for (int st=128; st>0; st>>=1){
        if (tid < st){
            #pragma unroll
            for (int e=0;e<E_N;e++) red[tid][e] += red[tid+st][e];
        }
        __syncthreads();
    }
    if (tid < E_N) ssum[b*E_N+tid] = red[0][tid];
}

// ---- h0/c0 (relu MLPs on ssum), scatter into state buffers ----
__global__ void k_init(const float* __restrict__ ssum, const float* __restrict__ f02w,
                       const float* __restrict__ f02b, const float* __restrict__ f03w,
                       const float* __restrict__ f03b,
                       unsigned short* __restrict__ Hbuf, float* __restrict__ C){
    int b = blockIdx.x, j = threadIdx.x;   // j in [0,1024)
    float sv[E_N];
    #pragma unroll
    for (int e=0;e<E_N;e++) sv[e] = ssum[b*E_N+e];
    float h = f02b[j], c = f03b[j];
    #pragma unroll
    for (int e=0;e<E_N;e++){ h += sv[e]*f02w[j*E_N+e]; c += sv[e]*f03w[j*E_N+e]; }
    h = h > 0.f ? h : 0.f;
    c = c > 0.f ? c : 0.f;
    int l = j >> 8, k = j & 255;
    // layer l is first read at wall-step w=l from parity (l&1)
    Hbuf[(((size_t)l*2 + (l&1))*B_N + b)*H_N + k] = f2bf(h);
    C[((size_t)l*B_N + b)*H_N + k] = c;
}

// ---- bias sum + zero the sync slots ----
__global__ void k_bias(const float* __restrict__ bih, const float* __restrict__ bhh,
                       float* __restrict__ bsum, int* __restrict__ slots){
    int i = blockIdx.x*256 + threadIdx.x;   // 4096
    bsum[i] = bih[i] + bhh[i];
    if (i < 256) slots[i] = 0;
}

// ---- coherent (L3 / coherence-point) access helpers: no cache maintenance ----
__device__ __forceinline__ void coh_load2(const unsigned short* p0, uint4& a0, uint4& a1){
    asm volatile(
        "global_load_dwordx4 %0, %2, off sc0 sc1\n\t"
        "global_load_dwordx4 %1, %3, off sc0 sc1\n\t"
        "s_waitcnt vmcnt(0)"
        : "=&v"(a0), "=&v"(a1)
        : "v"(p0), "v"(p0 + 8)
        : "memory");
}
__device__ __forceinline__ void coh_load4(const unsigned short* p0, const unsigned short* p1,
                                          uint4& a0, uint4& a1, uint4& b0, uint4& b1){
    asm volatile(
        "global_load_dwordx4 %0, %4, off sc0 sc1\n\t"
        "global_load_dwordx4 %1, %5, off sc0 sc1\n\t"
        "global_load_dwordx4 %2, %6, off sc0 sc1\n\t"
        "global_load_dwordx4 %3, %7, off sc0 sc1\n\t"
        "s_waitcnt vmcnt(0)"
        : "=&v"(a0), "=&v"(a1), "=&v"(b0), "=&v"(b1)
        : "v"(p0), "v"(p0 + 8), "v"(p1), "v"(p1 + 8)
        : "memory");
}
__device__ __forceinline__ void coh_store_short(unsigned short* p, unsigned short v){
    unsigned int vv = v;
    asm volatile("global_store_short %0, %1, off sc0 sc1" :: "v"(p), "v"(vv) : "memory");
}
__device__ __forceinline__ void coh_store_u32(int* p, int v){
    asm volatile("global_store_dword %0, %1, off sc0 sc1" :: "v"(p), "v"(v) : "memory");
}
__device__ __forceinline__ unsigned int coh_load_u32(const int* p){
    unsigned int v;
    asm volatile("global_load_dword %0, %1, off sc0 sc1\n\ts_waitcnt vmcnt(0)"
                 : "=v"(v) : "v"(p) : "memory");
    return v;
}
__device__ __forceinline__ void drain_vmem(){
    asm volatile("s_waitcnt vmcnt(0)" ::: "memory");
}

// ---- persistent wavefront LSTM ----
// grid 256 WGs: bg = bid&7 (sync group), kj = (bid>>3)&7, l = bid>>6
// block 256 = 4 waves; wave = gate. Weights live in VGPRs, c in registers.
__global__ __launch_bounds__(256) void k_lstm(
    const float* __restrict__ s,            // [S][B][E] f32
    const unsigned short* __restrict__ Wih, // [3][1024][256] bf16 (layers 1..3)
    const unsigned short* __restrict__ Whh, // [4][1024][256] bf16
    const float* __restrict__ Wih0,         // [1024][10] f32
    const float* __restrict__ bsum,         // [4][1024] f32
    unsigned short* __restrict__ Hbuf,      // [4][2][128][256] bf16
    const float* __restrict__ C,            // [4][128][256] f32 (init only)
    float* __restrict__ y,                  // [128][1024] f32 out
    int* slots)                             // [8][32] step flags
{
    __shared__ unsigned short hx[16*264];   // h tile
    __shared__ unsigned short xx[16*264];   // x tile (layers>=1)
    __shared__ float xs[16*E_N];            // layer-0 s tile
    __shared__ float gl[16*132];            // gates tile

    const int bid = blockIdx.x;
    const int bg = bid & 7, kj = (bid >> 3) & 7, l = bid >> 6;
    const int b0 = bg*16, k0 = kj*32;
    const int tid = threadIdx.x;
    const int wid = tid >> 6, lane = tid & 63;
    const int cl = lane & 15, kg = lane >> 4;
    const int j0 = wid*256 + k0 + cl, j1 = j0 + 16;

    const float bia0 = bsum[l*G4 + j0];
    const float bia1 = bsum[l*G4 + j1];

    // ---- weights -> registers (once) ----
    short8 wh0[8], wh1[8], wi0[8], wi1[8];
    {
        const unsigned short* p0 = Whh + ((size_t)l*G4 + j0)*H_N + kg*8;
        const unsigned short* p1 = Whh + ((size_t)l*G4 + j1)*H_N + kg*8;
        #pragma unroll
        for (int kt=0;kt<8;kt++){
            wh0[kt] = *(const short8*)(p0 + kt*32);
            wh1[kt] = *(const short8*)(p1 + kt*32);
        }
    }
    float w00[E_N], w01[E_N];
    if (l > 0){
        const unsigned short* q0 = Wih + ((size_t)(l-1)*G4 + j0)*H_N + kg*8;
        const unsigned short* q1 = Wih + ((size_t)(l-1)*G4 + j1)*H_N + kg*8;
        #pragma unroll
        for (int kt=0;kt<8;kt++){
            wi0[kt] = *(const short8*)(q0 + kt*32);
            wi1[kt] = *(const short8*)(q1 + kt*32);
        }
    } else {
        #pragma unroll
        for (int e=0;e<E_N;e++){
            w00[e] = Wih0[j0*E_N + e];
            w01[e] = Wih0[j1*E_N + e];
        }
    }

    // ---- private cell state in registers ----
    const int e0 = tid, e1 = tid + 256;
    const int br0 = e0 >> 5, ko0 = e0 & 31;
    const int br1 = e1 >> 5, ko1 = e1 & 31;
    const size_t BH = (size_t)B_N * H_N;
    const size_t ho0 = ((size_t)(l*2))*BH + (size_t)(b0+br0)*H_N + k0 + ko0;
    const size_t ho1 = ((size_t)(l*2))*BH + (size_t)(b0+br1)*H_N + k0 + ko1;
    float c0r = C[((size_t)l*B_N + b0 + br0)*H_N + k0 + ko0];
    float c1r = C[((size_t)l*B_N + b0 + br1)*H_N + k0 + ko1];

    int* const myslot  = slots + bg*32 + l*8 + kj;
    int* const bgslots = slots + bg*32;
    const int* const pollp = bgslots + (lane & 31);

    for (int w = 0; w < S_LEN + L_N - 1; ++w){
        const int t = w - l;
        const int p = w & 1;
        if (t >= 0 && t < S_LEN){
            // stage h (and x) tiles into LDS via coherence-point loads
            {
                const int r = tid >> 4, cs = tid & 15;
                const unsigned short* src = Hbuf + ((size_t)(l*2 + p))*BH + (size_t)(b0+r)*H_N + cs*16;
                uint4 a0, a1, x0, x1;
                if (l > 0){
                    const unsigned short* sx = Hbuf + ((size_t)((l-1)*2 + p))*BH + (size_t)(b0+r)*H_N + cs*16;
                    coh_load4(src, sx, a0, a1, x0, x1);
                    *(uint4*)&xx[r*264 + cs*16]     = x0;
                    *(uint4*)&xx[r*264 + cs*16 + 8] = x1;
                } else {
                    coh_load2(src, a0, a1);
                    if (tid < 16*E_N)
                        xs[tid] = s[((size_t)t*B_N + b0 + tid/E_N)*E_N + (tid%E_N)];
                }
                *(uint4*)&hx[r*264 + cs*16]     = a0;
                *(uint4*)&hx[r*264 + cs*16 + 8] = a1;
            }
            __syncthreads();

            f32x4 acc0 = {0.f,0.f,0.f,0.f};
            f32x4 acc1 = {0.f,0.f,0.f,0.f};
            if (l > 0){
                #pragma unroll
                for (int kt=0;kt<8;kt++){
                    const int kk = kt*32 + kg*8;
                    short8 ah = *(const short8*)&hx[cl*264 + kk];
                    short8 ax = *(const short8*)&xx[cl*264 + kk];
                    acc0 = __builtin_amdgcn_mfma_f32_16x16x32_bf16(ah, wh0[kt], acc0, 0,0,0);
                    acc1 = __builtin_amdgcn_mfma_f32_16x16x32_bf16(ah, wh1[kt], acc1, 0,0,0);
                    acc0 = __builtin_amdgcn_mfma_f32_16x16x32_bf16(ax, wi0[kt], acc0, 0,0,0);
                    acc1 = __builtin_amdgcn_mfma_f32_16x16x32_bf16(ax, wi1[kt], acc1, 0,0,0);
                }
            } else {
                #pragma unroll
                for (int kt=0;kt<8;kt++){
                    const int kk = kt*32 + kg*8;
                    short8 ah = *(const short8*)&hx[cl*264 + kk];
                    acc0 = __builtin_amdgcn_mfma_f32_16x16x32_bf16(ah, wh0[kt], acc0, 0,0,0);
                    acc1 = __builtin_amdgcn_mfma_f32_16x16x32_bf16(ah, wh1[kt], acc1, 0,0,0);
                }
            }

            #pragma unroll
            for (int r=0;r<4;r++){
                const int br = kg*4 + r;       // D: row=(lane>>4)*4+reg (batch), col=lane&15
                float v0 = acc0[r] + bia0;
                float v1 = acc1[r] + bia1;
                if (l == 0){
                    #pragma unroll
                    for (int e=0;e<E_N;e++){
                        const float sv = xs[br*E_N + e];
                        v0 += sv*w00[e];
                        v1 += sv*w01[e];
                    }
                }
                gl[br*132 + wid*32 + cl]      = v0;
                gl[br*132 + wid*32 + 16 + cl] = v1;
            }
            __syncthreads();

            // cell update: 2 private elements per thread; publish h at coherence point
            {
                float gi = gl[br0*132 +      ko0];
                float gf = gl[br0*132 + 32 + ko0];
                float gg = gl[br0*132 + 64 + ko0];
                float go = gl[br0*132 + 96 + ko0];
                float si = 1.f/(1.f + __expf(-gi));
                float sf = 1.f/(1.f + __expf(-gf));
                float sg = tanhf(gg);
                float so = 1.f/(1.f + __expf(-go));
                c0r = sf*c0r + si*sg;
                float hn = so*tanhf(c0r);
                coh_store_short(Hbuf + ho0 + (size_t)(p^1)*BH, f2bf(hn));
                if (t == S_LEN-1) y[(size_t)(b0+br0)*G4 + l*H_N + k0 + ko0] = hn;
            }
            {
                float gi = gl[br1*132 +      ko1];
                float gf = gl[br1*132 + 32 + ko1];
                float gg = gl[br1*132 + 64 + ko1];
                float go = gl[br1*132 + 96 + ko1];
                float si = 1.f/(1.f + __expf(-gi));
                float sf = 1.f/(1.f + __expf(-gf));
                float sg = tanhf(gg);
                float so = 1.f/(1.f + __expf(-go));
                c1r = sf*c1r + si*sg;
                float hn = so*tanhf(c1r);
                coh_store_short(Hbuf + ho1 + (size_t)(p^1)*BH, f2bf(hn));
                if (t == S_LEN-1) y[(size_t)(b0+br1)*G4 + l*H_N + k0 + ko1] = hn;
            }
        }
        drain_vmem();          // every wave: all h stores at coherence point
        __syncthreads();       // all waves drained before flag
        if (tid == 0){
            coh_store_u32(myslot, w + 1);
        }
        if (wid == 0){
            const int target = w + 1;
            int guard = 0;
            for(;;){
                unsigned int v = coh_load_u32(pollp);
                if (__all((int)v >= target)) break;
                if (++guard > (1<<18)) break;      // hang guard (never hit when co-resident)
            }
        }
        __syncthreads();
    }
}

extern "C" void kernel_launch(void* const* d_in, const int* in_sizes, int n_in,
                              void* d_out, int out_size, void* d_ws, size_t ws_size,
                              hipStream_t stream) {
    const int*   x      = (const int*)  d_in[0];
    const float* e01    = (const float*)d_in[1];
    const float* p01    = (const float*)d_in[2];
    const float* f01w   = (const float*)d_in[3];
    const float* f01b   = (const float*)d_in[4];
    const float* f02w   = (const float*)d_in[5];
    const float* f02b   = (const float*)d_in[6];
    const float* f03w   = (const float*)d_in[7];
    const float* f03b   = (const float*)d_in[8];
    const float* Wih0   = (const float*)d_in[9];
    const float* WihR   = (const float*)d_in[10];  // [3][1024][256]
    const float* Whh    = (const float*)d_in[11];  // [4][1024][256]
    const float* bih    = (const float*)d_in[12];
    const float* bhh    = (const float*)d_in[13];
    float* y = (float*)d_out;

    // workspace carve
    float* s_buf = (float*)d_ws;                          // 1,310,720 f
    float* ssum  = s_buf + (size_t)S_LEN*B_N*E_N;         // 1,280 f
    float* bsum  = ssum + B_N*E_N;                        // 4,096 f
    float* Cst   = bsum + L_N*G4;                         // 131,072 f
    int*   slots = (int*)(Cst + (size_t)L_N*B_N*H_N);     // 256 i
    unsigned short* Hbuf = (unsigned short*)(slots + 256);          // 262,144 us
    unsigned short* WbHH = Hbuf + (size_t)L_N*2*B_N*H_N;            // 1,048,576 us
    unsigned short* WbIH = WbHH + (size_t)L_N*G4*H_N;               // 786,432 us

    // weight conversion
    k_cvt<<<dim3(4096), dim3(256), 0, stream>>>(Whh,  WbHH, L_N*G4*H_N);
    k_cvt<<<dim3(3072), dim3(256), 0, stream>>>(WihR, WbIH, (L_N-1)*G4*H_N);

    // prologue
    k_prep_s<<<dim3((S_LEN*B_N)/256), dim3(256), 0, stream>>>(x, e01, p01, f01w, f01b, s_buf);
    k_ssum  <<<dim3(B_N), dim3(256), 0, stream>>>(s_buf, ssum);
    k_init  <<<dim3(B_N), dim3(1024), 0, stream>>>(ssum, f02w, f02b, f03w, f03b, Hbuf, Cst);
    k_bias  <<<dim3(16), dim3(256), 0, stream>>>(bih, bhh, bsum, slots);

    // persistent wavefront LSTM (one dispatch, co-resident grid)
    {
        const float* s_p = s_buf;
        const unsigned short* wih_p = WbIH;
        const unsigned short* whh_p = WbHH;
        const float* wih0_p = Wih0;
        const float* bsum_p = bsum;
        unsigned short* hbuf_p = Hbuf;
        const float* c_p = Cst;
        float* y_p = y;
        int* slots_p = slots;
        void* args[] = { &s_p, &wih_p, &whh_p, &wih0_p, &bsum_p, &hbuf_p, &c_p, &y_p, &slots_p };
        hipLaunchCooperativeKernel(reinterpret_cast<const void*>(&k_lstm),
                                   dim3(256), dim3(256), args, 0, stream);
    }
}